// Round 5
// baseline (179.066 us; speedup 1.0000x reference)
//
#include <hip/hip_runtime.h>
#include <hip/hip_bf16.h>

// ---------------------------------------------------------------------------
// Causal MHA forward.  B=2, T=2048, H=16, Dk=64, D=1024.  Inputs float32;
// internal pipeline bf16 MFMA.
// R17: attn T14 async-STAGE split: K/V staged via regs (issue loads for tile
//     t+1 during tile t's compute; ds_write after the post-compute barrier).
//     Removes the per-tile vmcnt(0)-in-barrier drain (~300-500cy x 17 tiles).
//     LDS layout byte-identical to GLD version (write at base+lane*16B, same
//     pre-swizzled global sources) -> QK/PV reads untouched.  LDS size and
//     2-blocks/CU occupancy unchanged.  +16 VGPR (reg tile in flight).
//     NOT applied to gemms (m249: reg-staging net-negative vs gload_lds).
//     R16 recap: gemm_out BK=128 + attn setprio, 171.2 -> 164.9.
//     prep / gemm128 frozen at R12; gemm_out frozen at R16.
//     launch_bounds min-waves MUST stay 4 (6 spilled twice: R6, R7).
// Workspace (u16 elements, 1M = 2^20), 40 MB:
//   [0,4M)   Xbf [4096][1024] bf16      (Ab aliases this after QKV)
//   [4M,7M)  Wqkv^T (3 x [1024][1024])
//   [7M,11M) Q   [11M,15M) K   [15M,19M) V^T [32][64][2048]
//   [19M,20M) Wo^T
// ---------------------------------------------------------------------------

typedef unsigned short u16;
typedef __bf16 bf16x8 __attribute__((ext_vector_type(8)));
typedef float f32x4 __attribute__((ext_vector_type(4)));
typedef u16 u16x4 __attribute__((ext_vector_type(4)));

#define TS 72               // padded LDS stride (transpose)
#define PS 136              // P-tile LDS stride (R5-proven)
#define NEG_INF (-1e30f)
#define SC_LOG2 0.1803368801f   // log2(e)/8  (exp2-domain softmax scale)

#if __has_builtin(__builtin_amdgcn_exp2f)
#define EXP2(x) __builtin_amdgcn_exp2f(x)
#else
#define EXP2(x) exp2f(x)
#endif

#define GLD_LDS16(gp, lp) __builtin_amdgcn_global_load_lds( \
    (const __attribute__((address_space(1))) void*)(gp),    \
    (__attribute__((address_space(3))) void*)(lp), 16, 0, 0)

__device__ __forceinline__ bf16x8 as_bf16x8(int4 v) { return __builtin_bit_cast(bf16x8, v); }
__device__ __forceinline__ u16 bf16_bits(float f) { return __builtin_bit_cast(u16, (__bf16)f); }

// Runtime dtype detect: f32-as-u16 low words have big exponent fields.
__device__ __forceinline__ bool detect_f32(const void* X) {
    const u16* x16 = (const u16*)X;
    int lane = threadIdx.x & 63;
    int hits = 0;
#pragma unroll
    for (int i = 0; i < 4; ++i) {
        u16 v = x16[lane * 4 + i];
        hits += (((v >> 7) & 0xFF) > 130) ? 1 : 0;
    }
    return __popcll(__ballot(hits > 0)) >= 8;
}

__device__ __forceinline__ bf16x8 load8(const void* p, size_t eoff, bool f32m) {
    if (!f32m) return as_bf16x8(*(const int4*)((const u16*)p + eoff));
    const float* f = (const float*)p + eoff;
    float4 a = *(const float4*)f;
    float4 b = *(const float4*)(f + 4);
    bf16x8 r;
    r[0] = (__bf16)a.x; r[1] = (__bf16)a.y; r[2] = (__bf16)a.z; r[3] = (__bf16)a.w;
    r[4] = (__bf16)b.x; r[5] = (__bf16)b.y; r[6] = (__bf16)b.z; r[7] = (__bf16)b.w;
    return r;
}

// ---------------- prep: 4 weight transposes (z=0..3) + X cvt (z=4) ----------
__global__ __launch_bounds__(256) void prep_all(const void* __restrict__ Wq,
                                                const void* __restrict__ Wk,
                                                const void* __restrict__ Wv,
                                                const void* __restrict__ Wo,
                                                const void* __restrict__ X,
                                                u16* __restrict__ Wt3,
                                                u16* __restrict__ Wot,
                                                u16* __restrict__ Xbf) {
    bool f32m = detect_f32(X);
    int z = blockIdx.z;
    if (z == 4) {
        int blk = blockIdx.y * 16 + blockIdx.x;
        size_t base = (size_t)blk * 16384 + threadIdx.x * 8;
#pragma unroll
        for (int i = 0; i < 8; ++i) {
            size_t eoff = base + (size_t)i * 2048;
            bf16x8 v = load8(X, eoff, f32m);
            *(int4*)(Xbf + eoff) = __builtin_bit_cast(int4, v);
        }
        return;
    }
    const void* in = (z == 0) ? Wq : (z == 1) ? Wk : (z == 2) ? Wv : Wo;
    u16* out = (z < 3) ? (Wt3 + (size_t)z * (1u << 20)) : Wot;
    __shared__ alignas(16) u16 T[64][TS];
    int r0 = blockIdx.y * 64, c0 = blockIdx.x * 64;
    int tr = threadIdx.x >> 3, tc8 = threadIdx.x & 7;
    bf16x8 v0 = load8(in, (size_t)(r0 + tr) * 1024 + c0 + tc8 * 8, f32m);
    bf16x8 v1 = load8(in, (size_t)(r0 + tr + 32) * 1024 + c0 + tc8 * 8, f32m);
    *(int4*)&T[tr][tc8 * 8]      = __builtin_bit_cast(int4, v0);
    *(int4*)&T[tr + 32][tc8 * 8] = __builtin_bit_cast(int4, v1);
    __syncthreads();
    for (int half = 0; half < 2; ++half) {
        int cr = tr + half * 32;
        u16 tmp[8];
#pragma unroll
        for (int i = 0; i < 8; ++i) tmp[i] = T[tc8 * 8 + i][cr];
        *(int4*)(out + (size_t)(c0 + cr) * 1024 + r0 + tc8 * 8) = *(int4*)tmp;
    }
}

// ---------------- 128x128-tile bf16 MFMA GEMM (QKV), XOR-swizzled LDS -------
// A: Xbf [4096][1024] bf16; Bt: Wqkv^T [3072][1024] bf16.  Pure GLD staging.
// 4 waves, each 64x64 subtile: 32 MFMA : 16 b128-reads per wave-iter.
__global__ __launch_bounds__(256, 4) void gemm128(const u16* __restrict__ A,
                                                  const u16* __restrict__ Bt,
                                                  u16* __restrict__ Cq, u16* __restrict__ Ck,
                                                  u16* __restrict__ Cv) {
    __shared__ alignas(16) u16 As[128 * 64];
    __shared__ alignas(16) u16 Bs[128 * 64];
    const int K = 1024;
    int tid = threadIdx.x, wave = tid >> 6, lane = tid & 63;
    int quad = lane >> 4, l16 = lane & 15;
    int wrow = wave >> 1, wcol = wave & 1;
    int m0 = blockIdx.x * 128, n0 = blockIdx.y * 128;
    int rlane = lane >> 3, kc = lane & 7;
    int scol = (kc ^ rlane) * 8;          // swizzled source column (u16)

    f32x4 acc[4][4] = {};

    for (int k0 = 0; k0 < K; k0 += 64) {
        __syncthreads();
#pragma unroll
        for (int i = 0; i < 4; ++i) {
            int rc = wave * 4 + i;       // 16 chunks of 8 rows each
            GLD_LDS16(A  + (size_t)(m0 + rc * 8 + rlane) * K + k0 + scol, As + rc * 512);
            GLD_LDS16(Bt + (size_t)(n0 + rc * 8 + rlane) * K + k0 + scol, Bs + rc * 512);
        }
        __syncthreads();
#pragma unroll
        for (int ks = 0; ks < 2; ++ks) {
            bf16x8 af[4], bfr[4];
#pragma unroll
            for (int i = 0; i < 4; ++i) {
                int row = wrow * 64 + i * 16 + l16;
                af[i] = as_bf16x8(*(const int4*)(As + row * 64 + (((ks * 4 + quad) ^ (row & 7)) * 8)));
            }
#pragma unroll
            for (int j = 0; j < 4; ++j) {
                int row = wcol * 64 + j * 16 + l16;
                bfr[j] = as_bf16x8(*(const int4*)(Bs + row * 64 + (((ks * 4 + quad) ^ (row & 7)) * 8)));
            }
#pragma unroll
            for (int i = 0; i < 4; ++i)
#pragma unroll
                for (int j = 0; j < 4; ++j)
                    acc[i][j] = __builtin_amdgcn_mfma_f32_16x16x32_bf16(af[i], bfr[j], acc[i][j], 0, 0, 0);
        }
    }

#pragma unroll
    for (int i = 0; i < 4; ++i)
#pragma unroll
        for (int j = 0; j < 4; ++j)
#pragma unroll
            for (int r = 0; r < 4; ++r) {
                int m = m0 + wrow * 64 + i * 16 + quad * 4 + r;
                int n = n0 + wcol * 64 + j * 16 + l16;
                float f = acc[i][j][r];
                if (n < 1024)       Cq[(size_t)m * 1024 + n] = bf16_bits(f);
                else if (n < 2048)  Ck[(size_t)m * 1024 + n - 1024] = bf16_bits(f);
                else {
                    int n2 = n - 2048;
                    int bh = ((m >> 11) << 4) | (n2 >> 6), d = n2 & 63, t = m & 2047;
                    Cv[(((size_t)bh * 64 + d) << 11) + t] = bf16_bits(f);
                }
            }
}

// ---------------- 64x128-tile GEMM (out-proj), R16: BK=128 ------------------
__global__ __launch_bounds__(256, 4) void gemm_out(const u16* __restrict__ A,
                                                   const u16* __restrict__ Bt,
                                                   void* __restrict__ Cout,
                                                   const void* __restrict__ Xdet) {
    bool f32m = detect_f32(Xdet);
    __shared__ alignas(16) u16 As[64 * 128];    // 16 KB
    __shared__ alignas(16) u16 Bs[128 * 128];   // 32 KB
    const int K = 1024;
    int tid = threadIdx.x, wave = tid >> 6, lane = tid & 63;
    int quad = lane >> 4, l16 = lane & 15;
    int wrow = wave & 1, wcol = wave >> 1;
    int m0 = blockIdx.x * 64, n0 = blockIdx.y * 128;
    int rlane4 = lane >> 4, kc16 = lane & 15;   // staging: 4 rows x 16 chunks

    f32x4 acc[2][4] = {};

    for (int k0 = 0; k0 < K; k0 += 128) {
        __syncthreads();
#pragma unroll
        for (int i = 0; i < 8; ++i) {           // B: 128 rows, 4 per GLD
            int rb = wave * 32 + i * 4;
            int grow = rb + rlane4;
            int gch = kc16 ^ (grow & 15);
            GLD_LDS16(Bt + (size_t)(n0 + grow) * K + k0 + gch * 8, Bs + rb * 128);
        }
#pragma unroll
        for (int i = 0; i < 4; ++i) {           // A: 64 rows, 4 per GLD
            int rb = wave * 16 + i * 4;
            int grow = rb + rlane4;
            int gch = kc16 ^ (grow & 15);
            GLD_LDS16(A + (size_t)(m0 + grow) * K + k0 + gch * 8, As + rb * 128);
        }
        __syncthreads();
#pragma unroll
        for (int ks = 0; ks < 4; ++ks) {
            bf16x8 af[2], bfr[4];
#pragma unroll
            for (int i = 0; i < 2; ++i) {
                int row = wrow * 32 + i * 16 + l16;
                af[i] = as_bf16x8(*(const int4*)(As + row * 128 + (((ks * 4 + quad) ^ (row & 15)) * 8)));
            }
#pragma unroll
            for (int j = 0; j < 4; ++j) {
                int row = wcol * 64 + j * 16 + l16;
                bfr[j] = as_bf16x8(*(const int4*)(Bs + row * 128 + (((ks * 4 + quad) ^ (row & 15)) * 8)));
            }
#pragma unroll
            for (int i = 0; i < 2; ++i)
#pragma unroll
                for (int j = 0; j < 4; ++j)
                    acc[i][j] = __builtin_amdgcn_mfma_f32_16x16x32_bf16(af[i], bfr[j], acc[i][j], 0, 0, 0);
        }
    }

#pragma unroll
    for (int i = 0; i < 2; ++i)
#pragma unroll
        for (int j = 0; j < 4; ++j)
#pragma unroll
            for (int r = 0; r < 4; ++r) {
                int m = m0 + wrow * 32 + i * 16 + quad * 4 + r;
                int n = n0 + wcol * 64 + j * 16 + l16;
                float f = acc[i][j][r];
                if (f32m) ((float*)Cout)[(size_t)m * 1024 + n] = f;
                else      ((u16*)Cout)[(size_t)m * 1024 + n] = bf16_bits(f);
            }
}

// ---------------- flash attention (R17: T14 reg-staged write-late) ----------
// Per tile: regs hold tile j2+1's K/V (loaded during j2's compute).  After
// the post-compute barrier: ds_write (compiler waits vmcnt -- overlapped),
// issue loads for j2+2, barrier.  LDS layout byte-identical to the GLD
// version (write at base+lane*16B, pre-swizzled global sources).
__global__ __launch_bounds__(512, 4) void attn_kernel(const u16* __restrict__ Qb,
                                                      const u16* __restrict__ Kb,
                                                      const u16* __restrict__ Vt,
                                                      u16* __restrict__ Ab) {
    __shared__ alignas(16) u16 Ks[128 * 64];   // swizzled [kv][d]
    __shared__ alignas(16) u16 Vs[64 * 128];   // swizzled [d][t]
    __shared__ alignas(16) u16 Ps[128 * PS];   // [q 128][kv 128] padded

    int tid = threadIdx.x, wave = tid >> 6, lane = tid & 63;
    int quad = lane >> 4, l16 = lane & 15;
    int bh = blockIdx.x;                 // x fastest => heavy-J blocks first
    // Complementary pairing: resident CU pairs (i, i+256) sum to 17 kv-iters.
    int J = (blockIdx.y < 8) ? (15 - (int)blockIdx.y) : ((int)blockIdx.y - 8);
    int b = bh >> 4, h = bh & 15;
    int q0 = J * 128;
    int kr4 = lane >> 3, kc = lane & 7;   // K staging: 8 rows x 8 chunks
    int vr4 = lane >> 4, vc = lane & 15;  // V staging: 4 rows x 16 chunks

    const u16* qrow = Qb + (size_t)(b * 2048 + q0 + wave * 16 + l16) * 1024 + h * 64;
    bf16x8 qa0 = as_bf16x8(*(const int4*)(qrow + quad * 8));
    bf16x8 qa1 = as_bf16x8(*(const int4*)(qrow + 32 + quad * 8));

    f32x4 o[4] = {};
    float psum = 0.0f;                   // lane-local: q = wave*16+l16

    const u16* kbase = Kb + (size_t)(b * 2048) * 1024 + h * 64;
    const u16* vbase = Vt + (size_t)bh * 64 * 2048;

    // staging geometry (i = 0,1), LDS dest identical to GLD_LDS16 layout:
    int rbk0 = (wave * 2 + 0) * 8, rbk1 = (wave * 2 + 1) * 8;
    int rbv0 = (wave * 2 + 0) * 4, rbv1 = (wave * 2 + 1) * 4;
    const u16* kgp0 = kbase + (size_t)(rbk0 + kr4) * 1024 + (kc ^ ((rbk0 + kr4) & 7)) * 8;
    const u16* kgp1 = kbase + (size_t)(rbk1 + kr4) * 1024 + (kc ^ ((rbk1 + kr4) & 7)) * 8;
    const u16* vgp0 = vbase + (size_t)(rbv0 + vr4) * 2048 + (vc ^ ((rbv0 + vr4) & 15)) * 8;
    const u16* vgp1 = vbase + (size_t)(rbv1 + vr4) * 2048 + (vc ^ ((rbv1 + vr4) & 15)) * 8;
    u16* klp0 = Ks + rbk0 * 64 + lane * 8;
    u16* klp1 = Ks + rbk1 * 64 + lane * 8;
    u16* vlp0 = Vs + rbv0 * 128 + lane * 8;
    u16* vlp1 = Vs + rbv1 * 128 + lane * 8;

    int4 kr0, kr1, vv0, vv1;             // in-flight reg tile
    // prologue: tile 0 -> regs -> LDS; issue tile 1; barrier.
    kr0 = *(const int4*)(kgp0);
    kr1 = *(const int4*)(kgp1);
    vv0 = *(const int4*)(vgp0);
    vv1 = *(const int4*)(vgp1);
    *(int4*)klp0 = kr0; *(int4*)klp1 = kr1;
    *(int4*)vlp0 = vv0; *(int4*)vlp1 = vv1;
    if (J >= 1) {
        kr0 = *(const int4*)(kgp0 + (size_t)128 * 1024);
        kr1 = *(const int4*)(kgp1 + (size_t)128 * 1024);
        vv0 = *(const int4*)(vgp0 + 128);
        vv1 = *(const int4*)(vgp1 + 128);
    }
    __syncthreads();

    for (int j2 = 0; j2 <= J; ++j2) {
        bool diag = (j2 == J);
        int ntc = diag ? ((wave & ~1) + 2) : 8;

        // S^T tile: s[nt][r] = S[kv = t0+nt*16+quad*4+r][q = q0+wave*16+l16]
        f32x4 s[8];
        __builtin_amdgcn_s_setprio(1);
#pragma unroll
        for (int nt = 0; nt < 8; ++nt) {
            if (nt >= ntc) continue;
            if (diag && nt > wave) {
                s[nt][0] = NEG_INF; s[nt][1] = NEG_INF; s[nt][2] = NEG_INF; s[nt][3] = NEG_INF;
                continue;
            }
            int row = nt * 16 + l16;
            int sw = row & 7;
            f32x4 a = {};
            bf16x8 b0 = as_bf16x8(*(const int4*)(Ks + row * 64 + ((quad ^ sw) * 8)));
            a = __builtin_amdgcn_mfma_f32_16x16x32_bf16(b0, qa0, a, 0, 0, 0);   // A=K, B=Q
            bf16x8 b1 = as_bf16x8(*(const int4*)(Ks + row * 64 + (((4 + quad) ^ sw) * 8)));
            a = __builtin_amdgcn_mfma_f32_16x16x32_bf16(b1, qa1, a, 0, 0, 0);
            a = a * SC_LOG2;
            if (diag && nt == wave) {
#pragma unroll
                for (int r = 0; r < 4; ++r)
                    if (quad * 4 + r > l16) a[r] = NEG_INF;
            }
            s[nt] = a;
        }
        __builtin_amdgcn_s_setprio(0);

        // softmax: all lane-local.  One ds_write_b64 per nt (4 packed bf16).
        int prow = (wave * 16 + l16) * PS;
#pragma unroll
        for (int nt = 0; nt < 8; ++nt) {
            if (nt >= ntc) continue;
            u16x4 pk;
            float ps4 = 0.0f;
#pragma unroll
            for (int r = 0; r < 4; ++r) {
                float p = EXP2(s[nt][r]);
                ps4 += p;
                pk[r] = bf16_bits(p);
            }
            psum += ps4;
            *(u16x4*)(Ps + prow + nt * 16 + quad * 4) = pk;
        }

        int ksm = ntc >> 1;
        __builtin_amdgcn_s_setprio(1);
#pragma unroll
        for (int ks = 0; ks < 4; ++ks) {
            if (ks >= ksm) continue;
            bf16x8 pa = as_bf16x8(*(const int4*)(Ps + (wave * 16 + l16) * PS + ks * 32 + quad * 8));
#pragma unroll
            for (int d4 = 0; d4 < 4; ++d4) {
                int vrow = d4 * 16 + l16;
                bf16x8 vb = as_bf16x8(*(const int4*)(Vs + vrow * 128 + (((ks * 4 + quad) ^ l16) * 8)));
                o[d4] = __builtin_amdgcn_mfma_f32_16x16x32_bf16(pa, vb, o[d4], 0, 0, 0);
            }
        }
        __builtin_amdgcn_s_setprio(0);

        if (j2 < J) {
            __syncthreads();             // all waves done reading Ks/Vs
            // write tile j2+1 (regs loaded during this tile's compute);
            // compiler inserts the vmcnt wait here -- fully overlapped.
            *(int4*)klp0 = kr0; *(int4*)klp1 = kr1;
            *(int4*)vlp0 = vv0; *(int4*)vlp1 = vv1;
            if (j2 + 2 <= J) {           // issue loads for tile j2+2
                size_t t0n = (size_t)(j2 + 2) * 128;
                kr0 = *(const int4*)(kgp0 + t0n * 1024);
                kr1 = *(const int4*)(kgp1 + t0n * 1024);
                vv0 = *(const int4*)(vgp0 + t0n);
                vv1 = *(const int4*)(vgp1 + t0n);
            }
            __syncthreads();             // tile j2+1 visible
        }
    }

    // denominators: reduce across quads (kv partition), redistribute to rows.
    psum += __shfl_xor(psum, 16);
    psum += __shfl_xor(psum, 32);        // now full denom for q = wave*16+l16

    u16* arow = Ab + (size_t)(b * 2048 + q0 + wave * 16) * 1024 + h * 64;
#pragma unroll
    for (int r = 0; r < 4; ++r) {
        float dn = __shfl(psum, quad * 4 + r, 16);   // denom for q row quad*4+r
        float inv = 1.0f / dn;
#pragma unroll
        for (int d4 = 0; d4 < 4; ++d4)
            arow[(quad * 4 + r) * 1024 + d4 * 16 + l16] = bf16_bits(o[d4][r] * inv);
    }
}

// ---------------------------------------------------------------------------
extern "C" void kernel_launch(void* const* d_in, const int* in_sizes, int n_in,
                              void* d_out, int out_size, void* d_ws, size_t ws_size,
                              hipStream_t stream) {
    (void)in_sizes; (void)n_in; (void)out_size; (void)ws_size;
    const void* X  = d_in[0];
    const void* Wq = d_in[1];
    const void* Wk = d_in[2];
    const void* Wv = d_in[3];
    const void* Wo = d_in[4];
    u16* ws16 = (u16*)d_ws;
    const size_t M1 = 1u << 20;
    u16* Xbf = ws16 + 0 * M1;        // [0,4M)
    u16* Wt3 = ws16 + 4 * M1;        // [4M,7M)
    u16* Qb  = ws16 + 7 * M1;
    u16* Kb  = ws16 + 11 * M1;
    u16* Vt  = ws16 + 15 * M1;
    u16* Wot = ws16 + 19 * M1;
    u16* Ab  = ws16 + 0 * M1;        // aliases Xbf (dead after QKV GEMM)

    prep_all<<<dim3(16, 16, 5), 256, 0, stream>>>(Wq, Wk, Wv, Wo, X, Wt3, Wot, Xbf);
    gemm128<<<dim3(32, 24), 256, 0, stream>>>(Xbf, Wt3, Qb, Kb, Vt);
    attn_kernel<<<dim3(32, 16), 512, 0, stream>>>(Qb, Kb, Vt, Ab);
    gemm_out<<<dim3(64, 8), 256, 0, stream>>>(Ab, Wot, d_out, X);
}

// Round 6
// 173.038 us; speedup vs baseline: 1.0348x; 1.0348x over previous
//
#include <hip/hip_runtime.h>
#include <hip/hip_bf16.h>

// ---------------------------------------------------------------------------
// Causal MHA forward.  B=2, T=2048, H=16, Dk=64, D=1024.  Inputs float32;
// internal pipeline bf16 MFMA.
// R18: attn: R17 reg-staging REVERTED (spilled: FETCH +3.9MB / WRITE +8.1MB
//     scratch traffic).  Instead: LDS double-buffered K/V with GLD staging
//     kept (zero extra VGPRs).  One __syncthreads per tile (was 2); its
//     implicit vmcnt(0) waits on GLDs issued BEFORE the compute phase ->
//     drain hidden.  LDS fits 2 blocks/CU via quarter-Ps: tile processed in
//     4 groups of 32 kv cols {QK 2nt -> exp2 -> Ps[128][40] -> PV 1ks},
//     Ps reuse is wave-internal (lgkmcnt-ordered, no barrier).  Buffers are
//     separate named arrays + 2x-unrolled loop => compile-time buffer
//     selection (alias analysis can disambiguate).  s[8]->s[2]: -24 VGPR.
//     LDS 74 KB (4x16K K/V + 10K Ps).  KVBLK stays 128 (R13 lesson).
//     R16 recap: gemm_out BK=128 + attn setprio, 164.9 us.
//     prep / gemm128 frozen at R12; gemm_out frozen at R16.
//     launch_bounds min-waves MUST stay 4 (6 spilled twice: R6, R7).
// Workspace (u16 elements, 1M = 2^20), 40 MB:
//   [0,4M)   Xbf [4096][1024] bf16      (Ab aliases this after QKV)
//   [4M,7M)  Wqkv^T (3 x [1024][1024])
//   [7M,11M) Q   [11M,15M) K   [15M,19M) V^T [32][64][2048]
//   [19M,20M) Wo^T
// ---------------------------------------------------------------------------

typedef unsigned short u16;
typedef __bf16 bf16x8 __attribute__((ext_vector_type(8)));
typedef float f32x4 __attribute__((ext_vector_type(4)));
typedef u16 u16x4 __attribute__((ext_vector_type(4)));

#define TS 72               // padded LDS stride (transpose)
#define PSQ 40              // quarter P-tile stride (32 cols + 8 pad)
#define NEG_INF (-1e30f)
#define SC_LOG2 0.1803368801f   // log2(e)/8  (exp2-domain softmax scale)

#if __has_builtin(__builtin_amdgcn_exp2f)
#define EXP2(x) __builtin_amdgcn_exp2f(x)
#else
#define EXP2(x) exp2f(x)
#endif

#define GLD_LDS16(gp, lp) __builtin_amdgcn_global_load_lds( \
    (const __attribute__((address_space(1))) void*)(gp),    \
    (__attribute__((address_space(3))) void*)(lp), 16, 0, 0)

__device__ __forceinline__ bf16x8 as_bf16x8(int4 v) { return __builtin_bit_cast(bf16x8, v); }
__device__ __forceinline__ u16 bf16_bits(float f) { return __builtin_bit_cast(u16, (__bf16)f); }

// Runtime dtype detect: f32-as-u16 low words have big exponent fields.
__device__ __forceinline__ bool detect_f32(const void* X) {
    const u16* x16 = (const u16*)X;
    int lane = threadIdx.x & 63;
    int hits = 0;
#pragma unroll
    for (int i = 0; i < 4; ++i) {
        u16 v = x16[lane * 4 + i];
        hits += (((v >> 7) & 0xFF) > 130) ? 1 : 0;
    }
    return __popcll(__ballot(hits > 0)) >= 8;
}

__device__ __forceinline__ bf16x8 load8(const void* p, size_t eoff, bool f32m) {
    if (!f32m) return as_bf16x8(*(const int4*)((const u16*)p + eoff));
    const float* f = (const float*)p + eoff;
    float4 a = *(const float4*)f;
    float4 b = *(const float4*)(f + 4);
    bf16x8 r;
    r[0] = (__bf16)a.x; r[1] = (__bf16)a.y; r[2] = (__bf16)a.z; r[3] = (__bf16)a.w;
    r[4] = (__bf16)b.x; r[5] = (__bf16)b.y; r[6] = (__bf16)b.z; r[7] = (__bf16)b.w;
    return r;
}

// ---------------- prep: 4 weight transposes (z=0..3) + X cvt (z=4) ----------
__global__ __launch_bounds__(256) void prep_all(const void* __restrict__ Wq,
                                                const void* __restrict__ Wk,
                                                const void* __restrict__ Wv,
                                                const void* __restrict__ Wo,
                                                const void* __restrict__ X,
                                                u16* __restrict__ Wt3,
                                                u16* __restrict__ Wot,
                                                u16* __restrict__ Xbf) {
    bool f32m = detect_f32(X);
    int z = blockIdx.z;
    if (z == 4) {
        int blk = blockIdx.y * 16 + blockIdx.x;
        size_t base = (size_t)blk * 16384 + threadIdx.x * 8;
#pragma unroll
        for (int i = 0; i < 8; ++i) {
            size_t eoff = base + (size_t)i * 2048;
            bf16x8 v = load8(X, eoff, f32m);
            *(int4*)(Xbf + eoff) = __builtin_bit_cast(int4, v);
        }
        return;
    }
    const void* in = (z == 0) ? Wq : (z == 1) ? Wk : (z == 2) ? Wv : Wo;
    u16* out = (z < 3) ? (Wt3 + (size_t)z * (1u << 20)) : Wot;
    __shared__ alignas(16) u16 T[64][TS];
    int r0 = blockIdx.y * 64, c0 = blockIdx.x * 64;
    int tr = threadIdx.x >> 3, tc8 = threadIdx.x & 7;
    bf16x8 v0 = load8(in, (size_t)(r0 + tr) * 1024 + c0 + tc8 * 8, f32m);
    bf16x8 v1 = load8(in, (size_t)(r0 + tr + 32) * 1024 + c0 + tc8 * 8, f32m);
    *(int4*)&T[tr][tc8 * 8]      = __builtin_bit_cast(int4, v0);
    *(int4*)&T[tr + 32][tc8 * 8] = __builtin_bit_cast(int4, v1);
    __syncthreads();
    for (int half = 0; half < 2; ++half) {
        int cr = tr + half * 32;
        u16 tmp[8];
#pragma unroll
        for (int i = 0; i < 8; ++i) tmp[i] = T[tc8 * 8 + i][cr];
        *(int4*)(out + (size_t)(c0 + cr) * 1024 + r0 + tc8 * 8) = *(int4*)tmp;
    }
}

// ---------------- 128x128-tile bf16 MFMA GEMM (QKV), XOR-swizzled LDS -------
// A: Xbf [4096][1024] bf16; Bt: Wqkv^T [3072][1024] bf16.  Pure GLD staging.
// 4 waves, each 64x64 subtile: 32 MFMA : 16 b128-reads per wave-iter.
__global__ __launch_bounds__(256, 4) void gemm128(const u16* __restrict__ A,
                                                  const u16* __restrict__ Bt,
                                                  u16* __restrict__ Cq, u16* __restrict__ Ck,
                                                  u16* __restrict__ Cv) {
    __shared__ alignas(16) u16 As[128 * 64];
    __shared__ alignas(16) u16 Bs[128 * 64];
    const int K = 1024;
    int tid = threadIdx.x, wave = tid >> 6, lane = tid & 63;
    int quad = lane >> 4, l16 = lane & 15;
    int wrow = wave >> 1, wcol = wave & 1;
    int m0 = blockIdx.x * 128, n0 = blockIdx.y * 128;
    int rlane = lane >> 3, kc = lane & 7;
    int scol = (kc ^ rlane) * 8;          // swizzled source column (u16)

    f32x4 acc[4][4] = {};

    for (int k0 = 0; k0 < K; k0 += 64) {
        __syncthreads();
#pragma unroll
        for (int i = 0; i < 4; ++i) {
            int rc = wave * 4 + i;       // 16 chunks of 8 rows each
            GLD_LDS16(A  + (size_t)(m0 + rc * 8 + rlane) * K + k0 + scol, As + rc * 512);
            GLD_LDS16(Bt + (size_t)(n0 + rc * 8 + rlane) * K + k0 + scol, Bs + rc * 512);
        }
        __syncthreads();
#pragma unroll
        for (int ks = 0; ks < 2; ++ks) {
            bf16x8 af[4], bfr[4];
#pragma unroll
            for (int i = 0; i < 4; ++i) {
                int row = wrow * 64 + i * 16 + l16;
                af[i] = as_bf16x8(*(const int4*)(As + row * 64 + (((ks * 4 + quad) ^ (row & 7)) * 8)));
            }
#pragma unroll
            for (int j = 0; j < 4; ++j) {
                int row = wcol * 64 + j * 16 + l16;
                bfr[j] = as_bf16x8(*(const int4*)(Bs + row * 64 + (((ks * 4 + quad) ^ (row & 7)) * 8)));
            }
#pragma unroll
            for (int i = 0; i < 4; ++i)
#pragma unroll
                for (int j = 0; j < 4; ++j)
                    acc[i][j] = __builtin_amdgcn_mfma_f32_16x16x32_bf16(af[i], bfr[j], acc[i][j], 0, 0, 0);
        }
    }

#pragma unroll
    for (int i = 0; i < 4; ++i)
#pragma unroll
        for (int j = 0; j < 4; ++j)
#pragma unroll
            for (int r = 0; r < 4; ++r) {
                int m = m0 + wrow * 64 + i * 16 + quad * 4 + r;
                int n = n0 + wcol * 64 + j * 16 + l16;
                float f = acc[i][j][r];
                if (n < 1024)       Cq[(size_t)m * 1024 + n] = bf16_bits(f);
                else if (n < 2048)  Ck[(size_t)m * 1024 + n - 1024] = bf16_bits(f);
                else {
                    int n2 = n - 2048;
                    int bh = ((m >> 11) << 4) | (n2 >> 6), d = n2 & 63, t = m & 2047;
                    Cv[(((size_t)bh * 64 + d) << 11) + t] = bf16_bits(f);
                }
            }
}

// ---------------- 64x128-tile GEMM (out-proj), R16: BK=128 ------------------
__global__ __launch_bounds__(256, 4) void gemm_out(const u16* __restrict__ A,
                                                   const u16* __restrict__ Bt,
                                                   void* __restrict__ Cout,
                                                   const void* __restrict__ Xdet) {
    bool f32m = detect_f32(Xdet);
    __shared__ alignas(16) u16 As[64 * 128];    // 16 KB
    __shared__ alignas(16) u16 Bs[128 * 128];   // 32 KB
    const int K = 1024;
    int tid = threadIdx.x, wave = tid >> 6, lane = tid & 63;
    int quad = lane >> 4, l16 = lane & 15;
    int wrow = wave & 1, wcol = wave >> 1;
    int m0 = blockIdx.x * 64, n0 = blockIdx.y * 128;
    int rlane4 = lane >> 4, kc16 = lane & 15;   // staging: 4 rows x 16 chunks

    f32x4 acc[2][4] = {};

    for (int k0 = 0; k0 < K; k0 += 128) {
        __syncthreads();
#pragma unroll
        for (int i = 0; i < 8; ++i) {           // B: 128 rows, 4 per GLD
            int rb = wave * 32 + i * 4;
            int grow = rb + rlane4;
            int gch = kc16 ^ (grow & 15);
            GLD_LDS16(Bt + (size_t)(n0 + grow) * K + k0 + gch * 8, Bs + rb * 128);
        }
#pragma unroll
        for (int i = 0; i < 4; ++i) {           // A: 64 rows, 4 per GLD
            int rb = wave * 16 + i * 4;
            int grow = rb + rlane4;
            int gch = kc16 ^ (grow & 15);
            GLD_LDS16(A + (size_t)(m0 + grow) * K + k0 + gch * 8, As + rb * 128);
        }
        __syncthreads();
#pragma unroll
        for (int ks = 0; ks < 4; ++ks) {
            bf16x8 af[2], bfr[4];
#pragma unroll
            for (int i = 0; i < 2; ++i) {
                int row = wrow * 32 + i * 16 + l16;
                af[i] = as_bf16x8(*(const int4*)(As + row * 128 + (((ks * 4 + quad) ^ (row & 15)) * 8)));
            }
#pragma unroll
            for (int j = 0; j < 4; ++j) {
                int row = wcol * 64 + j * 16 + l16;
                bfr[j] = as_bf16x8(*(const int4*)(Bs + row * 128 + (((ks * 4 + quad) ^ (row & 15)) * 8)));
            }
#pragma unroll
            for (int i = 0; i < 2; ++i)
#pragma unroll
                for (int j = 0; j < 4; ++j)
                    acc[i][j] = __builtin_amdgcn_mfma_f32_16x16x32_bf16(af[i], bfr[j], acc[i][j], 0, 0, 0);
        }
    }

#pragma unroll
    for (int i = 0; i < 2; ++i)
#pragma unroll
        for (int j = 0; j < 4; ++j)
#pragma unroll
            for (int r = 0; r < 4; ++r) {
                int m = m0 + wrow * 32 + i * 16 + quad * 4 + r;
                int n = n0 + wcol * 64 + j * 16 + l16;
                float f = acc[i][j][r];
                if (f32m) ((float*)Cout)[(size_t)m * 1024 + n] = f;
                else      ((u16*)Cout)[(size_t)m * 1024 + n] = bf16_bits(f);
            }
}

// ---------------- flash attention (R18: GLD dbuf + quarter-Ps) --------------
// Per tile: issue next tile's 4 GLDs -> compute (4 groups of {QK 2nt ->
// softmax -> Ps -> PV 1ks}) -> ONE __syncthreads (its vmcnt(0) drain is
// hidden under the compute phase).  Buffers are separate named arrays with
// compile-time selection (2x-unrolled j2 loop).

#define STAGE_TILE(KSBUF, VSBUF, T0)                                           \
    {                                                                          \
        _Pragma("unroll")                                                      \
        for (int i_ = 0; i_ < 2; ++i_) {                                       \
            int rb_ = (wave * 2 + i_) * 8;                                     \
            int grow_ = rb_ + kr4;                                             \
            int gch_ = kc ^ (grow_ & 7);                                       \
            GLD_LDS16(kbase + (size_t)((T0) + grow_) * 1024 + gch_ * 8,        \
                      KSBUF + rb_ * 64);                                       \
        }                                                                      \
        _Pragma("unroll")                                                      \
        for (int i_ = 0; i_ < 2; ++i_) {                                       \
            int rb_ = (wave * 2 + i_) * 4;                                     \
            int grow_ = rb_ + vr4;                                             \
            int gch_ = vc ^ (grow_ & 15);                                      \
            GLD_LDS16(vbase + (size_t)grow_ * 2048 + (T0) + gch_ * 8,          \
                      VSBUF + rb_ * 128);                                      \
        }                                                                      \
    }

#define COMPUTE_TILE(KS, VS, DIAG, NTC)                                        \
    {                                                                          \
        _Pragma("unroll")                                                      \
        for (int g = 0; g < 4; ++g) {                                          \
            if (2 * g >= (NTC)) continue;                                      \
            f32x4 sg0, sg1;                                                    \
            __builtin_amdgcn_s_setprio(1);                                     \
            _Pragma("unroll")                                                  \
            for (int h2 = 0; h2 < 2; ++h2) {                                   \
                int nt = 2 * g + h2;                                           \
                f32x4 a = {};                                                  \
                if ((DIAG) && nt > wave) {                                     \
                    a[0] = NEG_INF; a[1] = NEG_INF;                            \
                    a[2] = NEG_INF; a[3] = NEG_INF;                            \
                } else {                                                       \
                    int row = nt * 16 + l16;                                   \
                    int sw = row & 7;                                          \
                    bf16x8 b0 = as_bf16x8(*(const int4*)((KS) + row * 64 + ((quad ^ sw) * 8)));       \
                    a = __builtin_amdgcn_mfma_f32_16x16x32_bf16(b0, qa0, a, 0, 0, 0);                 \
                    bf16x8 b1 = as_bf16x8(*(const int4*)((KS) + row * 64 + (((4 + quad) ^ sw) * 8))); \
                    a = __builtin_amdgcn_mfma_f32_16x16x32_bf16(b1, qa1, a, 0, 0, 0);                 \
                    a = a * SC_LOG2;                                           \
                    if ((DIAG) && nt == wave) {                                \
                        _Pragma("unroll")                                      \
                        for (int r = 0; r < 4; ++r)                            \
                            if (quad * 4 + r > l16) a[r] = NEG_INF;            \
                    }                                                          \
                }                                                              \
                if (h2 == 0) sg0 = a; else sg1 = a;                            \
            }                                                                  \
            __builtin_amdgcn_s_setprio(0);                                     \
            _Pragma("unroll")                                                  \
            for (int h2 = 0; h2 < 2; ++h2) {                                   \
                f32x4 sv = h2 ? sg1 : sg0;                                     \
                u16x4 pk;                                                      \
                float ps4 = 0.0f;                                              \
                _Pragma("unroll")                                              \
                for (int r = 0; r < 4; ++r) {                                  \
                    float p = EXP2(sv[r]);                                     \
                    ps4 += p;                                                  \
                    pk[r] = bf16_bits(p);                                      \
                }                                                              \
                psum += ps4;                                                   \
                *(u16x4*)(Ps + prow + h2 * 16 + quad * 4) = pk;                \
            }                                                                  \
            __builtin_amdgcn_s_setprio(1);                                     \
            {                                                                  \
                bf16x8 pa = as_bf16x8(*(const int4*)(Ps + prow + quad * 8));   \
                _Pragma("unroll")                                              \
                for (int d4 = 0; d4 < 4; ++d4) {                               \
                    int vrow = d4 * 16 + l16;                                  \
                    bf16x8 vb = as_bf16x8(*(const int4*)((VS) + vrow * 128 + (((g * 4 + quad) ^ l16) * 8))); \
                    o[d4] = __builtin_amdgcn_mfma_f32_16x16x32_bf16(pa, vb, o[d4], 0, 0, 0);          \
                }                                                              \
            }                                                                  \
            __builtin_amdgcn_s_setprio(0);                                     \
        }                                                                      \
    }

__global__ __launch_bounds__(512, 4) void attn_kernel(const u16* __restrict__ Qb,
                                                      const u16* __restrict__ Kb,
                                                      const u16* __restrict__ Vt,
                                                      u16* __restrict__ Ab) {
    __shared__ alignas(16) u16 Ks0[128 * 64];  // swizzled [kv][d], buffer 0
    __shared__ alignas(16) u16 Ks1[128 * 64];  // buffer 1
    __shared__ alignas(16) u16 Vs0[64 * 128];  // swizzled [d][t], buffer 0
    __shared__ alignas(16) u16 Vs1[64 * 128];  // buffer 1
    __shared__ alignas(16) u16 Ps[128 * PSQ];  // [q 128][kv 32] quarter, padded

    int tid = threadIdx.x, wave = tid >> 6, lane = tid & 63;
    int quad = lane >> 4, l16 = lane & 15;
    int bh = blockIdx.x;                 // x fastest => heavy-J blocks first
    // Complementary pairing: resident CU pairs (i, i+256) sum to 17 kv-iters.
    int J = (blockIdx.y < 8) ? (15 - (int)blockIdx.y) : ((int)blockIdx.y - 8);
    int b = bh >> 4, h = bh & 15;
    int q0 = J * 128;
    int kr4 = lane >> 3, kc = lane & 7;   // K staging: 8 rows x 8 chunks
    int vr4 = lane >> 4, vc = lane & 15;  // V staging: 4 rows x 16 chunks

    const u16* qrow = Qb + (size_t)(b * 2048 + q0 + wave * 16 + l16) * 1024 + h * 64;
    bf16x8 qa0 = as_bf16x8(*(const int4*)(qrow + quad * 8));
    bf16x8 qa1 = as_bf16x8(*(const int4*)(qrow + 32 + quad * 8));

    f32x4 o[4] = {};
    float psum = 0.0f;                   // lane-local: q = wave*16+l16
    int prow = (wave * 16 + l16) * PSQ;

    const u16* kbase = Kb + (size_t)(b * 2048) * 1024 + h * 64;
    const u16* vbase = Vt + (size_t)bh * 64 * 2048;

    // prologue: tile 0 into buffer 0 (drain exposed once).
    STAGE_TILE(Ks0, Vs0, 0);
    __syncthreads();

    for (int j2 = 0; j2 <= J; j2 += 2) {
        // ---- sub-iter A: compute tile j2 from buf0; prefetch j2+1 -> buf1
        if (j2 + 1 <= J) STAGE_TILE(Ks1, Vs1, (j2 + 1) * 128);
        {
            bool diag = (j2 == J);
            int ntc = diag ? ((wave & ~1) + 2) : 8;
            COMPUTE_TILE(Ks0, Vs0, diag, ntc);
        }
        __syncthreads();                 // buf1 loads done; buf0 free
        if (j2 + 1 > J) break;
        // ---- sub-iter B: compute tile j2+1 from buf1; prefetch j2+2 -> buf0
        if (j2 + 2 <= J) STAGE_TILE(Ks0, Vs0, (j2 + 2) * 128);
        {
            bool diag = (j2 + 1 == J);
            int ntc = diag ? ((wave & ~1) + 2) : 8;
            COMPUTE_TILE(Ks1, Vs1, diag, ntc);
        }
        __syncthreads();                 // buf0 loads done; buf1 free
    }

    // denominators: reduce across quads (kv partition), redistribute to rows.
    psum += __shfl_xor(psum, 16);
    psum += __shfl_xor(psum, 32);        // now full denom for q = wave*16+l16

    u16* arow = Ab + (size_t)(b * 2048 + q0 + wave * 16) * 1024 + h * 64;
#pragma unroll
    for (int r = 0; r < 4; ++r) {
        float dn = __shfl(psum, quad * 4 + r, 16);   // denom for q row quad*4+r
        float inv = 1.0f / dn;
#pragma unroll
        for (int d4 = 0; d4 < 4; ++d4)
            arow[(quad * 4 + r) * 1024 + d4 * 16 + l16] = bf16_bits(o[d4][r] * inv);
    }
}

// ---------------------------------------------------------------------------
extern "C" void kernel_launch(void* const* d_in, const int* in_sizes, int n_in,
                              void* d_out, int out_size, void* d_ws, size_t ws_size,
                              hipStream_t stream) {
    (void)in_sizes; (void)n_in; (void)out_size; (void)ws_size;
    const void* X  = d_in[0];
    const void* Wq = d_in[1];
    const void* Wk = d_in[2];
    const void* Wv = d_in[3];
    const void* Wo = d_in[4];
    u16* ws16 = (u16*)d_ws;
    const size_t M1 = 1u << 20;
    u16* Xbf = ws16 + 0 * M1;        // [0,4M)
    u16* Wt3 = ws16 + 4 * M1;        // [4M,7M)
    u16* Qb  = ws16 + 7 * M1;
    u16* Kb  = ws16 + 11 * M1;
    u16* Vt  = ws16 + 15 * M1;
    u16* Wot = ws16 + 19 * M1;
    u16* Ab  = ws16 + 0 * M1;        // aliases Xbf (dead after QKV GEMM)

    prep_all<<<dim3(16, 16, 5), 256, 0, stream>>>(Wq, Wk, Wv, Wo, X, Wt3, Wot, Xbf);
    gemm128<<<dim3(32, 24), 256, 0, stream>>>(Xbf, Wt3, Qb, Kb, Vt);
    attn_kernel<<<dim3(32, 16), 512, 0, stream>>>(Qb, Kb, Vt, Ab);
    gemm_out<<<dim3(64, 8), 256, 0, stream>>>(Ab, Wot, d_out, X);
}

// Round 7
// 171.550 us; speedup vs baseline: 1.0438x; 1.0087x over previous
//
#include <hip/hip_runtime.h>
#include <hip/hip_bf16.h>

// ---------------------------------------------------------------------------
// Causal MHA forward.  B=2, T=2048, H=16, Dk=64, D=1024.  Inputs float32;
// internal pipeline bf16 MFMA.
// R19: attn grid reshape: QBLK 128->64, 256-thr/4-wave blocks, 1024 blocks
//     (32 bh x 32 q-tiles, LPT heavy-first).  Per-wave datapath is R16
//     verbatim (16 q-rows/wave, same staging/QK/softmax/PV/epilogue); only
//     decomposition changes.  LDS 50.2KB -> 3 blocks/CU resident with ~4
//     blocks/CU of supply -> dynamic refill kills the solo-heavy-block tail
//     (R14/R16 occupancy stuck at 24.7%).  Diag: wave's q-chunk within the
//     128-kv diag tile is wq = 4*(Jq&1)+wave; ntc/mask otherwise unchanged.
//     R17 (reg-stage) and R18 (dbuf+quarterPs) both failed to beat R16's
//     simple 2-barrier structure; this keeps it.
//     prep / gemm128 frozen at R12; gemm_out frozen at R16 (164.9 us best).
//     launch_bounds min-waves MUST stay 4 (6 spilled twice: R6, R7).
// Workspace (u16 elements, 1M = 2^20), 40 MB:
//   [0,4M)   Xbf [4096][1024] bf16      (Ab aliases this after QKV)
//   [4M,7M)  Wqkv^T (3 x [1024][1024])
//   [7M,11M) Q   [11M,15M) K   [15M,19M) V^T [32][64][2048]
//   [19M,20M) Wo^T
// ---------------------------------------------------------------------------

typedef unsigned short u16;
typedef __bf16 bf16x8 __attribute__((ext_vector_type(8)));
typedef float f32x4 __attribute__((ext_vector_type(4)));
typedef u16 u16x4 __attribute__((ext_vector_type(4)));

#define TS 72               // padded LDS stride (transpose)
#define PS 136              // P-tile LDS stride (R5-proven)
#define NEG_INF (-1e30f)
#define SC_LOG2 0.1803368801f   // log2(e)/8  (exp2-domain softmax scale)

#if __has_builtin(__builtin_amdgcn_exp2f)
#define EXP2(x) __builtin_amdgcn_exp2f(x)
#else
#define EXP2(x) exp2f(x)
#endif

#define GLD_LDS16(gp, lp) __builtin_amdgcn_global_load_lds( \
    (const __attribute__((address_space(1))) void*)(gp),    \
    (__attribute__((address_space(3))) void*)(lp), 16, 0, 0)

__device__ __forceinline__ bf16x8 as_bf16x8(int4 v) { return __builtin_bit_cast(bf16x8, v); }
__device__ __forceinline__ u16 bf16_bits(float f) { return __builtin_bit_cast(u16, (__bf16)f); }

// Runtime dtype detect: f32-as-u16 low words have big exponent fields.
__device__ __forceinline__ bool detect_f32(const void* X) {
    const u16* x16 = (const u16*)X;
    int lane = threadIdx.x & 63;
    int hits = 0;
#pragma unroll
    for (int i = 0; i < 4; ++i) {
        u16 v = x16[lane * 4 + i];
        hits += (((v >> 7) & 0xFF) > 130) ? 1 : 0;
    }
    return __popcll(__ballot(hits > 0)) >= 8;
}

__device__ __forceinline__ bf16x8 load8(const void* p, size_t eoff, bool f32m) {
    if (!f32m) return as_bf16x8(*(const int4*)((const u16*)p + eoff));
    const float* f = (const float*)p + eoff;
    float4 a = *(const float4*)f;
    float4 b = *(const float4*)(f + 4);
    bf16x8 r;
    r[0] = (__bf16)a.x; r[1] = (__bf16)a.y; r[2] = (__bf16)a.z; r[3] = (__bf16)a.w;
    r[4] = (__bf16)b.x; r[5] = (__bf16)b.y; r[6] = (__bf16)b.z; r[7] = (__bf16)b.w;
    return r;
}

// ---------------- prep: 4 weight transposes (z=0..3) + X cvt (z=4) ----------
__global__ __launch_bounds__(256) void prep_all(const void* __restrict__ Wq,
                                                const void* __restrict__ Wk,
                                                const void* __restrict__ Wv,
                                                const void* __restrict__ Wo,
                                                const void* __restrict__ X,
                                                u16* __restrict__ Wt3,
                                                u16* __restrict__ Wot,
                                                u16* __restrict__ Xbf) {
    bool f32m = detect_f32(X);
    int z = blockIdx.z;
    if (z == 4) {
        int blk = blockIdx.y * 16 + blockIdx.x;
        size_t base = (size_t)blk * 16384 + threadIdx.x * 8;
#pragma unroll
        for (int i = 0; i < 8; ++i) {
            size_t eoff = base + (size_t)i * 2048;
            bf16x8 v = load8(X, eoff, f32m);
            *(int4*)(Xbf + eoff) = __builtin_bit_cast(int4, v);
        }
        return;
    }
    const void* in = (z == 0) ? Wq : (z == 1) ? Wk : (z == 2) ? Wv : Wo;
    u16* out = (z < 3) ? (Wt3 + (size_t)z * (1u << 20)) : Wot;
    __shared__ alignas(16) u16 T[64][TS];
    int r0 = blockIdx.y * 64, c0 = blockIdx.x * 64;
    int tr = threadIdx.x >> 3, tc8 = threadIdx.x & 7;
    bf16x8 v0 = load8(in, (size_t)(r0 + tr) * 1024 + c0 + tc8 * 8, f32m);
    bf16x8 v1 = load8(in, (size_t)(r0 + tr + 32) * 1024 + c0 + tc8 * 8, f32m);
    *(int4*)&T[tr][tc8 * 8]      = __builtin_bit_cast(int4, v0);
    *(int4*)&T[tr + 32][tc8 * 8] = __builtin_bit_cast(int4, v1);
    __syncthreads();
    for (int half = 0; half < 2; ++half) {
        int cr = tr + half * 32;
        u16 tmp[8];
#pragma unroll
        for (int i = 0; i < 8; ++i) tmp[i] = T[tc8 * 8 + i][cr];
        *(int4*)(out + (size_t)(c0 + cr) * 1024 + r0 + tc8 * 8) = *(int4*)tmp;
    }
}

// ---------------- 128x128-tile bf16 MFMA GEMM (QKV), XOR-swizzled LDS -------
// A: Xbf [4096][1024] bf16; Bt: Wqkv^T [3072][1024] bf16.  Pure GLD staging.
// 4 waves, each 64x64 subtile: 32 MFMA : 16 b128-reads per wave-iter.
__global__ __launch_bounds__(256, 4) void gemm128(const u16* __restrict__ A,
                                                  const u16* __restrict__ Bt,
                                                  u16* __restrict__ Cq, u16* __restrict__ Ck,
                                                  u16* __restrict__ Cv) {
    __shared__ alignas(16) u16 As[128 * 64];
    __shared__ alignas(16) u16 Bs[128 * 64];
    const int K = 1024;
    int tid = threadIdx.x, wave = tid >> 6, lane = tid & 63;
    int quad = lane >> 4, l16 = lane & 15;
    int wrow = wave >> 1, wcol = wave & 1;
    int m0 = blockIdx.x * 128, n0 = blockIdx.y * 128;
    int rlane = lane >> 3, kc = lane & 7;
    int scol = (kc ^ rlane) * 8;          // swizzled source column (u16)

    f32x4 acc[4][4] = {};

    for (int k0 = 0; k0 < K; k0 += 64) {
        __syncthreads();
#pragma unroll
        for (int i = 0; i < 4; ++i) {
            int rc = wave * 4 + i;       // 16 chunks of 8 rows each
            GLD_LDS16(A  + (size_t)(m0 + rc * 8 + rlane) * K + k0 + scol, As + rc * 512);
            GLD_LDS16(Bt + (size_t)(n0 + rc * 8 + rlane) * K + k0 + scol, Bs + rc * 512);
        }
        __syncthreads();
#pragma unroll
        for (int ks = 0; ks < 2; ++ks) {
            bf16x8 af[4], bfr[4];
#pragma unroll
            for (int i = 0; i < 4; ++i) {
                int row = wrow * 64 + i * 16 + l16;
                af[i] = as_bf16x8(*(const int4*)(As + row * 64 + (((ks * 4 + quad) ^ (row & 7)) * 8)));
            }
#pragma unroll
            for (int j = 0; j < 4; ++j) {
                int row = wcol * 64 + j * 16 + l16;
                bfr[j] = as_bf16x8(*(const int4*)(Bs + row * 64 + (((ks * 4 + quad) ^ (row & 7)) * 8)));
            }
#pragma unroll
            for (int i = 0; i < 4; ++i)
#pragma unroll
                for (int j = 0; j < 4; ++j)
                    acc[i][j] = __builtin_amdgcn_mfma_f32_16x16x32_bf16(af[i], bfr[j], acc[i][j], 0, 0, 0);
        }
    }

#pragma unroll
    for (int i = 0; i < 4; ++i)
#pragma unroll
        for (int j = 0; j < 4; ++j)
#pragma unroll
            for (int r = 0; r < 4; ++r) {
                int m = m0 + wrow * 64 + i * 16 + quad * 4 + r;
                int n = n0 + wcol * 64 + j * 16 + l16;
                float f = acc[i][j][r];
                if (n < 1024)       Cq[(size_t)m * 1024 + n] = bf16_bits(f);
                else if (n < 2048)  Ck[(size_t)m * 1024 + n - 1024] = bf16_bits(f);
                else {
                    int n2 = n - 2048;
                    int bh = ((m >> 11) << 4) | (n2 >> 6), d = n2 & 63, t = m & 2047;
                    Cv[(((size_t)bh * 64 + d) << 11) + t] = bf16_bits(f);
                }
            }
}

// ---------------- 64x128-tile GEMM (out-proj), R16: BK=128 ------------------
__global__ __launch_bounds__(256, 4) void gemm_out(const u16* __restrict__ A,
                                                   const u16* __restrict__ Bt,
                                                   void* __restrict__ Cout,
                                                   const void* __restrict__ Xdet) {
    bool f32m = detect_f32(Xdet);
    __shared__ alignas(16) u16 As[64 * 128];    // 16 KB
    __shared__ alignas(16) u16 Bs[128 * 128];   // 32 KB
    const int K = 1024;
    int tid = threadIdx.x, wave = tid >> 6, lane = tid & 63;
    int quad = lane >> 4, l16 = lane & 15;
    int wrow = wave & 1, wcol = wave >> 1;
    int m0 = blockIdx.x * 64, n0 = blockIdx.y * 128;
    int rlane4 = lane >> 4, kc16 = lane & 15;   // staging: 4 rows x 16 chunks

    f32x4 acc[2][4] = {};

    for (int k0 = 0; k0 < K; k0 += 128) {
        __syncthreads();
#pragma unroll
        for (int i = 0; i < 8; ++i) {           // B: 128 rows, 4 per GLD
            int rb = wave * 32 + i * 4;
            int grow = rb + rlane4;
            int gch = kc16 ^ (grow & 15);
            GLD_LDS16(Bt + (size_t)(n0 + grow) * K + k0 + gch * 8, Bs + rb * 128);
        }
#pragma unroll
        for (int i = 0; i < 4; ++i) {           // A: 64 rows, 4 per GLD
            int rb = wave * 16 + i * 4;
            int grow = rb + rlane4;
            int gch = kc16 ^ (grow & 15);
            GLD_LDS16(A + (size_t)(m0 + grow) * K + k0 + gch * 8, As + rb * 128);
        }
        __syncthreads();
#pragma unroll
        for (int ks = 0; ks < 4; ++ks) {
            bf16x8 af[2], bfr[4];
#pragma unroll
            for (int i = 0; i < 2; ++i) {
                int row = wrow * 32 + i * 16 + l16;
                af[i] = as_bf16x8(*(const int4*)(As + row * 128 + (((ks * 4 + quad) ^ (row & 15)) * 8)));
            }
#pragma unroll
            for (int j = 0; j < 4; ++j) {
                int row = wcol * 64 + j * 16 + l16;
                bfr[j] = as_bf16x8(*(const int4*)(Bs + row * 128 + (((ks * 4 + quad) ^ (row & 15)) * 8)));
            }
#pragma unroll
            for (int i = 0; i < 2; ++i)
#pragma unroll
                for (int j = 0; j < 4; ++j)
                    acc[i][j] = __builtin_amdgcn_mfma_f32_16x16x32_bf16(af[i], bfr[j], acc[i][j], 0, 0, 0);
        }
    }

#pragma unroll
    for (int i = 0; i < 2; ++i)
#pragma unroll
        for (int j = 0; j < 4; ++j)
#pragma unroll
            for (int r = 0; r < 4; ++r) {
                int m = m0 + wrow * 32 + i * 16 + quad * 4 + r;
                int n = n0 + wcol * 64 + j * 16 + l16;
                float f = acc[i][j][r];
                if (f32m) ((float*)Cout)[(size_t)m * 1024 + n] = f;
                else      ((u16*)Cout)[(size_t)m * 1024 + n] = bf16_bits(f);
            }
}

// ---------------- flash attention (R19: QBLK=64, 4-wave blocks) -------------
// 1024 blocks (32 bh x 32 q-tiles of 64 rows), LPT heavy-first.  Per wave:
// 16 q rows, identical datapath to R16.  kv tiles stay 128-wide; diag tile's
// q-chunk offset is wq = 4*(Jq&1)+wave.
__global__ __launch_bounds__(256, 4) void attn_kernel(const u16* __restrict__ Qb,
                                                      const u16* __restrict__ Kb,
                                                      const u16* __restrict__ Vt,
                                                      u16* __restrict__ Ab) {
    __shared__ alignas(16) u16 Ks[128 * 64];   // swizzled [kv][d]    16 KB
    __shared__ alignas(16) u16 Vs[64 * 128];   // swizzled [d][t]     16 KB
    __shared__ alignas(16) u16 Ps[64 * PS];    // [q 64][kv 128] pad  17 KB

    int tid = threadIdx.x, wave = tid >> 6, lane = tid & 63;
    int quad = lane >> 4, l16 = lane & 15;
    int bh = blockIdx.x;                 // x fastest => all bh of a q-tile together
    int Jq = 31 - (int)blockIdx.y;       // LPT: heaviest q-tiles dispatch first
    int b = bh >> 4, h = bh & 15;
    int q0 = Jq * 64;
    int NJ = (Jq >> 1) + 1;              // number of 128-wide kv tiles
    int kr4 = lane >> 3, kc = lane & 7;   // K staging: 8 rows x 8 chunks
    int vr4 = lane >> 4, vc = lane & 15;  // V staging: 4 rows x 16 chunks

    const u16* qrow = Qb + (size_t)(b * 2048 + q0 + wave * 16 + l16) * 1024 + h * 64;
    bf16x8 qa0 = as_bf16x8(*(const int4*)(qrow + quad * 8));
    bf16x8 qa1 = as_bf16x8(*(const int4*)(qrow + 32 + quad * 8));

    f32x4 o[4] = {};
    float psum = 0.0f;                   // lane-local: q = q0 + wave*16 + l16

    const u16* kbase = Kb + (size_t)(b * 2048) * 1024 + h * 64;
    const u16* vbase = Vt + (size_t)bh * 64 * 2048;

    int wq = ((Jq & 1) << 2) + wave;     // q-chunk within the diag 128-kv tile

    for (int j2 = 0; j2 < NJ; ++j2) {
        int t0 = j2 * 128;
        __syncthreads();
#pragma unroll
        for (int i = 0; i < 4; ++i) {        // K: 128 rows, 8 per GLD
            int rb = (wave * 4 + i) * 8;
            int grow = rb + kr4;
            int gch = kc ^ (grow & 7);
            GLD_LDS16(kbase + (size_t)(t0 + grow) * 1024 + gch * 8, Ks + rb * 64);
        }
#pragma unroll
        for (int i = 0; i < 4; ++i) {        // V: 64 rows, 4 per GLD
            int rb = (wave * 4 + i) * 4;
            int grow = rb + vr4;
            int gch = vc ^ (grow & 15);
            GLD_LDS16(vbase + (size_t)grow * 2048 + t0 + gch * 8, Vs + rb * 128);
        }
        __syncthreads();

        bool diag = (j2 == NJ - 1);
        int ntc = diag ? ((wq & ~1) + 2) : 8;

        // S^T tile: s[nt][r] = S[kv = t0+nt*16+quad*4+r][q = q0+wave*16+l16]
        f32x4 s[8];
        __builtin_amdgcn_s_setprio(1);
#pragma unroll
        for (int nt = 0; nt < 8; ++nt) {
            if (nt >= ntc) continue;
            if (diag && nt > wq) {
                s[nt][0] = NEG_INF; s[nt][1] = NEG_INF; s[nt][2] = NEG_INF; s[nt][3] = NEG_INF;
                continue;
            }
            int row = nt * 16 + l16;
            int sw = row & 7;
            f32x4 a = {};
            bf16x8 b0 = as_bf16x8(*(const int4*)(Ks + row * 64 + ((quad ^ sw) * 8)));
            a = __builtin_amdgcn_mfma_f32_16x16x32_bf16(b0, qa0, a, 0, 0, 0);   // A=K, B=Q
            bf16x8 b1 = as_bf16x8(*(const int4*)(Ks + row * 64 + (((4 + quad) ^ sw) * 8)));
            a = __builtin_amdgcn_mfma_f32_16x16x32_bf16(b1, qa1, a, 0, 0, 0);
            a = a * SC_LOG2;
            if (diag && nt == wq) {
#pragma unroll
                for (int r = 0; r < 4; ++r)
                    if (quad * 4 + r > l16) a[r] = NEG_INF;
            }
            s[nt] = a;
        }
        __builtin_amdgcn_s_setprio(0);

        // softmax: all lane-local.  One ds_write_b64 per nt (4 packed bf16).
        int prow = (wave * 16 + l16) * PS;
#pragma unroll
        for (int nt = 0; nt < 8; ++nt) {
            if (nt >= ntc) continue;
            u16x4 pk;
            float ps4 = 0.0f;
#pragma unroll
            for (int r = 0; r < 4; ++r) {
                float p = EXP2(s[nt][r]);
                ps4 += p;
                pk[r] = bf16_bits(p);
            }
            psum += ps4;
            *(u16x4*)(Ps + prow + nt * 16 + quad * 4) = pk;
        }

        int ksm = ntc >> 1;
        __builtin_amdgcn_s_setprio(1);
#pragma unroll
        for (int ks = 0; ks < 4; ++ks) {
            if (ks >= ksm) continue;
            bf16x8 pa = as_bf16x8(*(const int4*)(Ps + (wave * 16 + l16) * PS + ks * 32 + quad * 8));
#pragma unroll
            for (int d4 = 0; d4 < 4; ++d4) {
                int vrow = d4 * 16 + l16;
                bf16x8 vb = as_bf16x8(*(const int4*)(Vs + vrow * 128 + (((ks * 4 + quad) ^ l16) * 8)));
                o[d4] = __builtin_amdgcn_mfma_f32_16x16x32_bf16(pa, vb, o[d4], 0, 0, 0);
            }
        }
        __builtin_amdgcn_s_setprio(0);
    }

    // denominators: reduce across quads (kv partition), redistribute to rows.
    psum += __shfl_xor(psum, 16);
    psum += __shfl_xor(psum, 32);        // now full denom for q = q0+wave*16+l16

    u16* arow = Ab + (size_t)(b * 2048 + q0 + wave * 16) * 1024 + h * 64;
#pragma unroll
    for (int r = 0; r < 4; ++r) {
        float dn = __shfl(psum, quad * 4 + r, 16);   // denom for q row quad*4+r
        float inv = 1.0f / dn;
#pragma unroll
        for (int d4 = 0; d4 < 4; ++d4)
            arow[(quad * 4 + r) * 1024 + d4 * 16 + l16] = bf16_bits(o[d4][r] * inv);
    }
}

// ---------------------------------------------------------------------------
extern "C" void kernel_launch(void* const* d_in, const int* in_sizes, int n_in,
                              void* d_out, int out_size, void* d_ws, size_t ws_size,
                              hipStream_t stream) {
    (void)in_sizes; (void)n_in; (void)out_size; (void)ws_size;
    const void* X  = d_in[0];
    const void* Wq = d_in[1];
    const void* Wk = d_in[2];
    const void* Wv = d_in[3];
    const void* Wo = d_in[4];
    u16* ws16 = (u16*)d_ws;
    const size_t M1 = 1u << 20;
    u16* Xbf = ws16 + 0 * M1;        // [0,4M)
    u16* Wt3 = ws16 + 4 * M1;        // [4M,7M)
    u16* Qb  = ws16 + 7 * M1;
    u16* Kb  = ws16 + 11 * M1;
    u16* Vt  = ws16 + 15 * M1;
    u16* Wot = ws16 + 19 * M1;
    u16* Ab  = ws16 + 0 * M1;        // aliases Xbf (dead after QKV GEMM)

    prep_all<<<dim3(16, 16, 5), 256, 0, stream>>>(Wq, Wk, Wv, Wo, X, Wt3, Wot, Xbf);
    gemm128<<<dim3(32, 24), 256, 0, stream>>>(Xbf, Wt3, Qb, Kb, Vt);
    attn_kernel<<<dim3(32, 32), 256, 0, stream>>>(Qb, Kb, Vt, Ab);
    gemm_out<<<dim3(64, 8), 256, 0, stream>>>(Ab, Wot, d_out, X);
}